// Round 2
// baseline (1410.739 us; speedup 1.0000x reference)
//
#include <hip/hip_runtime.h>
#include <hip/hip_bf16.h>

#define T_STEPS 512
#define BATCH   2048
#define DIN     128
#define NH      16
#define COMB    (DIN + NH)
#define ROWS    (T_STEPS * BATCH)

__device__ __forceinline__ float rcpf(float x)  { return __builtin_amdgcn_rcpf(x); }
__device__ __forceinline__ float sigmf(float x) { return rcpf(1.f + __expf(-x)); }
__device__ __forceinline__ float tanhf_(float x){ float e = __expf(2.f * x); return (e - 1.f) * rcpf(e + 1.f); }

// value from lane (k - D) within the 16-lane row; lanes k < D receive 1.0f (mul identity)
template <int D>
__device__ __forceinline__ float scan_shr(float v) {
    int r = __builtin_amdgcn_update_dpp(0x3f800000, __float_as_int(v),
                                        0x110 | D, 0xF, 0xF, false);
    return __int_as_float(r);
}

__device__ __forceinline__ float zcvt(float v)            { return v; }
__device__ __forceinline__ float zcvt(__hip_bfloat16 v)   { return __bfloat162float(v); }
__device__ __forceinline__ void  zstore(float* p, float v){ *p = v; }
__device__ __forceinline__ void  zstore(__hip_bfloat16* p, float v){ *p = __float2bfloat16(v); }

// ---------------------------------------------------------------------------
// Phase 1: Zx[r][g][k] = sum_j x[r][j] * W_g[k][j] + b_g[k] + theta_g[k]
// r = t*BATCH + b, fully parallel. Lane (q,k): q = K-chunk of 32, k = output.
// ---------------------------------------------------------------------------
template <typename ZT>
__global__ __launch_bounds__(256, 2) void qlstm_phase1(
    const float* __restrict__ x,
    const float* __restrict__ Wf, const float* __restrict__ bf,
    const float* __restrict__ Wi, const float* __restrict__ bi,
    const float* __restrict__ Wu, const float* __restrict__ bu,
    const float* __restrict__ Wo, const float* __restrict__ bo,
    const float* __restrict__ thf, const float* __restrict__ thi,
    const float* __restrict__ thu, const float* __restrict__ tho,
    ZT* __restrict__ Zx)
{
    const int lane = threadIdx.x & 63;
    const int k    = lane & 15;
    const int q    = lane >> 4;
    const int gw   = blockIdx.x * 4 + (threadIdx.x >> 6);
    const int NW   = gridDim.x * 4;
    const int R    = ROWS / NW;                  // rows per wave (2048 blks -> 128)

    const float* Wg[4] = {Wf, Wi, Wu, Wo};
    float w[4][32];
#pragma unroll
    for (int g = 0; g < 4; ++g) {
        const float* Wr = Wg[g] + k * COMB + q * 32;
#pragma unroll
        for (int j = 0; j < 32; ++j) w[g][j] = Wr[j];
    }
    const float* bgq[4] = {bf, bi, bu, bo};
    const float* tgq[4] = {thf, thi, thu, tho};
    const float bt = bgq[q][k] + tgq[q][k];      // this lane stores gate q, elem k

    const size_t r0 = (size_t)gw * R;
    const float* xp = x + r0 * DIN + q * 32;

    float cvA[32], cvB[32];
    auto loadx = [&](float (&cv)[32], int i) {
        const float* p = xp + (size_t)i * DIN;
#pragma unroll
        for (int j4 = 0; j4 < 8; ++j4) {
            const float4 v = *(const float4*)(p + j4 * 4);
            cv[j4 * 4 + 0] = v.x; cv[j4 * 4 + 1] = v.y;
            cv[j4 * 4 + 2] = v.z; cv[j4 * 4 + 3] = v.w;
        }
    };
    auto dorow = [&](int i, float (&cv)[32]) {
        float acc[4] = {0.f, 0.f, 0.f, 0.f};
#pragma unroll
        for (int j = 0; j < 32; ++j)
#pragma unroll
            for (int g = 0; g < 4; ++g) acc[g] += cv[j] * w[g][j];
#pragma unroll
        for (int g = 0; g < 4; ++g) {
            acc[g] += __shfl_xor(acc[g], 16, 64);
            acc[g] += __shfl_xor(acc[g], 32, 64);
        }
        const float my = (q == 0) ? acc[0] : (q == 1) ? acc[1]
                       : (q == 2) ? acc[2] : acc[3];
        zstore(&Zx[(r0 + i) * 64 + lane], my + bt);   // fully coalesced 256B/wave
    };

    loadx(cvA, 0);
    for (int i = 0; i < R; i += 2) {
        loadx(cvB, i + 1);                            // R even -> always valid
        dorow(i, cvA);
        loadx(cvA, i + 2 < R ? i + 2 : R - 1);        // clamped prefetch
        dorow(i + 1, cvB);
    }
}

// ---------------------------------------------------------------------------
// Phase 2: the recurrence. One wave per batch element. Lane (q,k).
// Per step: acc = h @ Wh.T (K=16 split over q) + Zx, cos, cumprod, gates.
// ---------------------------------------------------------------------------
template <typename ZT>
__global__ __launch_bounds__(64, 2) void qlstm_phase2(
    const ZT* __restrict__ Zx,
    const float* __restrict__ Wf, const float* __restrict__ Wi,
    const float* __restrict__ Wu, const float* __restrict__ Wo,
    float* __restrict__ out)
{
    const int lane = threadIdx.x;
    const int k    = lane & 15;
    const int q    = lane >> 4;
    const int b    = blockIdx.x;

    const float* Wg[4] = {Wf, Wi, Wu, Wo};
    float wh[4][4];
#pragma unroll
    for (int g = 0; g < 4; ++g)
#pragma unroll
        for (int kk = 0; kk < 4; ++kk)
            wh[g][kk] = Wg[g][k * COMB + DIN + q * 4 + kk];

    float h = 0.f, c = 0.f;
    float zA[4], zB[4];
    auto loadz = [&](float (&z)[4], int t) {
        const ZT* p = Zx + ((size_t)t * BATCH + b) * 64 + k;
#pragma unroll
        for (int g = 0; g < 4; ++g) z[g] = zcvt(p[g * 16]);
    };

    float* op = out + (size_t)b * NH + k;

    auto step = [&](float (&z)[4]) {
        float acc[4] = {0.f, 0.f, 0.f, 0.f};
#pragma unroll
        for (int kk = 0; kk < 4; ++kk) {
            const float hv = __shfl(h, q * 4 + kk, 64);
#pragma unroll
            for (int g = 0; g < 4; ++g) acc[g] += hv * wh[g][kk];
        }
#pragma unroll
        for (int g = 0; g < 4; ++g) {
            acc[g] += __shfl_xor(acc[g], 16, 64);
            acc[g] += __shfl_xor(acc[g], 32, 64);
            acc[g] = __cosf(acc[g] + z[g]);
        }
#pragma unroll
        for (int g = 0; g < 4; ++g) {
            acc[g] *= scan_shr<1>(acc[g]);
            acc[g] *= scan_shr<2>(acc[g]);
            acc[g] *= scan_shr<4>(acc[g]);
            acc[g] *= scan_shr<8>(acc[g]);
        }
        const float f  = sigmf(acc[0]);
        const float i_ = sigmf(acc[1]);
        const float u  = tanhf_(acc[2]);
        const float o  = sigmf(acc[3]);
        c = f * c + i_ * u;
        h = o * tanhf_(c);
        if (q == 0) *op = h;
        op += (size_t)BATCH * NH;
    };

    loadz(zA, 0);
    for (int t = 0; t < T_STEPS; t += 2) {
        loadz(zB, t + 1);
        step(zA);
        loadz(zA, t + 2 < T_STEPS ? t + 2 : T_STEPS - 1);
        step(zB);
    }

    if (q == 0) {
        const size_t base = (size_t)T_STEPS * BATCH * NH;
        out[base + (size_t)b * NH + k] = h;
        out[base + (size_t)BATCH * NH + (size_t)b * NH + k] = c;
    }
}

// ---------------------------------------------------------------------------
// Fallback: round-1 monolithic kernel (proven correct) if d_ws is too small.
// ---------------------------------------------------------------------------
__global__ __launch_bounds__(64, 2) void qlstm_mono(
    const float* __restrict__ x,
    const float* __restrict__ Wf, const float* __restrict__ bf,
    const float* __restrict__ Wi, const float* __restrict__ bi,
    const float* __restrict__ Wu, const float* __restrict__ bu,
    const float* __restrict__ Wo, const float* __restrict__ bo,
    const float* __restrict__ thf, const float* __restrict__ thi,
    const float* __restrict__ thu, const float* __restrict__ tho,
    float* __restrict__ out)
{
    const int lane = threadIdx.x;
    const int k    = lane & 15;
    const int q    = lane >> 4;
    const int b    = blockIdx.x;

    const float* Wg[4] = {Wf, Wi, Wu, Wo};
    const float* bg[4] = {bf, bi, bu, bo};
    const float* tg[4] = {thf, thi, thu, tho};

    float w[4][32], wh[4][4], bt[4];
#pragma unroll
    for (int g = 0; g < 4; ++g) {
        const float* Wr = Wg[g] + k * COMB;
#pragma unroll
        for (int j = 0; j < 32; ++j) w[g][j] = Wr[q * 32 + j];
#pragma unroll
        for (int kk = 0; kk < 4; ++kk) wh[g][kk] = Wr[DIN + q * 4 + kk];
        bt[g] = bg[g][k] + tg[g][k];
    }

    float h = 0.f, c = 0.f;
    float cvA[32], cvB[32];
    auto xrow = [&](int t) -> const float* {
        return x + ((size_t)t * BATCH + b) * DIN + q * 32;
    };
    auto loadx = [&](float (&cv)[32], const float* p) {
#pragma unroll
        for (int j4 = 0; j4 < 8; ++j4) {
            const float4 v = *(const float4*)(p + j4 * 4);
            cv[j4 * 4 + 0] = v.x; cv[j4 * 4 + 1] = v.y;
            cv[j4 * 4 + 2] = v.z; cv[j4 * 4 + 3] = v.w;
        }
    };

    float* op = out + (size_t)b * NH + k;
    auto step = [&](int t, float (&cv)[32]) {
        float acc[4] = {0.f, 0.f, 0.f, 0.f};
#pragma unroll
        for (int j = 0; j < 32; ++j)
#pragma unroll
            for (int g = 0; g < 4; ++g) acc[g] += cv[j] * w[g][j];
#pragma unroll
        for (int kk = 0; kk < 4; ++kk) {
            const float hv = __shfl(h, q * 4 + kk, 64);
#pragma unroll
            for (int g = 0; g < 4; ++g) acc[g] += hv * wh[g][kk];
        }
#pragma unroll
        for (int g = 0; g < 4; ++g) {
            acc[g] += __shfl_xor(acc[g], 16, 64);
            acc[g] += __shfl_xor(acc[g], 32, 64);
            acc[g] = __cosf(acc[g] + bt[g]);
        }
#pragma unroll
        for (int g = 0; g < 4; ++g) {
            acc[g] *= scan_shr<1>(acc[g]);
            acc[g] *= scan_shr<2>(acc[g]);
            acc[g] *= scan_shr<4>(acc[g]);
            acc[g] *= scan_shr<8>(acc[g]);
        }
        const float f  = sigmf(acc[0]);
        const float i_ = sigmf(acc[1]);
        const float u  = tanhf_(acc[2]);
        const float o  = sigmf(acc[3]);
        c = f * c + i_ * u;
        h = o * tanhf_(c);
        if (q == 0) *op = h;
        op += (size_t)BATCH * NH;
    };

    loadx(cvA, xrow(0));
    for (int t = 0; t < T_STEPS; t += 2) {
        loadx(cvB, xrow(t + 1));
        step(t, cvA);
        const int tn = (t + 2 < T_STEPS) ? t + 2 : T_STEPS - 1;
        loadx(cvA, xrow(tn));
        step(t + 1, cvB);
    }
    if (q == 0) {
        const size_t base = (size_t)T_STEPS * BATCH * NH;
        out[base + (size_t)b * NH + k] = h;
        out[base + (size_t)BATCH * NH + (size_t)b * NH + k] = c;
    }
}

extern "C" void kernel_launch(void* const* d_in, const int* in_sizes, int n_in,
                              void* d_out, int out_size, void* d_ws, size_t ws_size,
                              hipStream_t stream) {
    const float* x   = (const float*)d_in[0];
    const float* Wf  = (const float*)d_in[1];
    const float* bf  = (const float*)d_in[2];
    const float* Wi  = (const float*)d_in[3];
    const float* bi  = (const float*)d_in[4];
    const float* Wu  = (const float*)d_in[5];
    const float* bu  = (const float*)d_in[6];
    const float* Wo  = (const float*)d_in[7];
    const float* bo  = (const float*)d_in[8];
    const float* thf = (const float*)d_in[9];
    const float* thi = (const float*)d_in[10];
    const float* thu = (const float*)d_in[11];
    const float* tho = (const float*)d_in[12];
    float* out = (float*)d_out;

    const size_t need_f32  = (size_t)ROWS * 64 * sizeof(float);           // 268 MB
    const size_t need_bf16 = (size_t)ROWS * 64 * sizeof(__hip_bfloat16);  // 134 MB

    if (ws_size >= need_f32) {
        float* Zx = (float*)d_ws;
        qlstm_phase1<float><<<dim3(2048), dim3(256), 0, stream>>>(
            x, Wf, bf, Wi, bi, Wu, bu, Wo, bo, thf, thi, thu, tho, Zx);
        qlstm_phase2<float><<<dim3(BATCH), dim3(64), 0, stream>>>(
            Zx, Wf, Wi, Wu, Wo, out);
    } else if (ws_size >= need_bf16) {
        __hip_bfloat16* Zx = (__hip_bfloat16*)d_ws;
        qlstm_phase1<__hip_bfloat16><<<dim3(2048), dim3(256), 0, stream>>>(
            x, Wf, bf, Wi, bi, Wu, bu, Wo, bo, thf, thi, thu, tho, Zx);
        qlstm_phase2<__hip_bfloat16><<<dim3(BATCH), dim3(64), 0, stream>>>(
            Zx, Wf, Wi, Wu, Wo, out);
    } else {
        qlstm_mono<<<dim3(BATCH), dim3(64), 0, stream>>>(
            x, Wf, bf, Wi, bi, Wu, bu, Wo, bo, thf, thi, thu, tho, out);
    }
}